// Round 4
// baseline (97.853 us; speedup 1.0000x reference)
//
#include <hip/hip_runtime.h>

#define NB 4      // B
#define NS 512    // S
#define NSC 128   // SC
#define NMC 64    // MC
#define NR 32     // R
#define NO 64     // O
#define NHID 256  // 4*O

typedef float f4 __attribute__((ext_vector_type(4)));

__device__ __forceinline__ float wave_sum(float v) {
    #pragma unroll
    for (int m = 1; m < 64; m <<= 1) v += __shfl_xor(v, m, 64);
    return v;
}
__device__ __forceinline__ float wave_max(float v) {
    #pragma unroll
    for (int m = 1; m < 64; m <<= 1) v = fmaxf(v, __shfl_xor(v, m, 64));
    return v;
}

// --- K1: q,k projections: one block (64 thr) per (b,s) row --------------
__global__ __launch_bounds__(64) void qk_kernel(
    const float* __restrict__ seq,
    const float* __restrict__ Wq, const float* __restrict__ bq,
    const float* __restrict__ Wk, const float* __restrict__ bk,
    float* __restrict__ q, float* __restrict__ k) {
    int bs  = blockIdx.x;
    int tid = threadIdx.x;
    __shared__ float srow[NSC];
    const float* sp = seq + (size_t)bs * NSC;
    srow[tid]      = sp[tid];
    srow[tid + 64] = sp[tid + 64];
    __syncthreads();
    int r = tid & 31;
    const float* W    = (tid < 32) ? Wq : Wk;
    const float* bias = (tid < 32) ? bq : bk;
    float acc = bias[r];
    #pragma unroll 8
    for (int c = 0; c < NSC; ++c) acc += srow[c] * W[c * NR + r];
    float* dst = (tid < 32) ? q : k;
    dst[(size_t)bs * NR + r] = acc;
}

// --- K2: softmax attention rows -> ws (one block per (b,s), 256 thr) ----
__global__ __launch_bounds__(256) void attn_kernel(
    const float* __restrict__ q, const float* __restrict__ k,
    float* __restrict__ attn) {
    const float DENOM_INV = 0.17677669529663687f;  // 1/sqrt(32)
    int bs   = blockIdx.x;
    int b    = bs >> 9;
    int tid  = threadIdx.x;
    int lane = tid & 63;
    int wave = tid >> 6;

    __shared__ float s_q[NR];
    __shared__ float s_red[8];
    if (tid < NR) s_q[tid] = q[(size_t)bs * NR + tid];
    __syncthreads();

    const float* kb = k + (size_t)b * NS * NR;
    const f4* q4 = (const f4*)s_q;
    const f4* k0 = (const f4*)(kb + (size_t)tid * NR);
    const f4* k1 = (const f4*)(kb + (size_t)(tid + 256) * NR);
    float a0 = 0.f, a1 = 0.f;
    #pragma unroll
    for (int r4 = 0; r4 < NR / 4; ++r4) {
        f4 qv = q4[r4], kv0 = k0[r4], kv1 = k1[r4];
        a0 += qv.x * kv0.x + qv.y * kv0.y + qv.z * kv0.z + qv.w * kv0.w;
        a1 += qv.x * kv1.x + qv.y * kv1.y + qv.z * kv1.z + qv.w * kv1.w;
    }
    float lg0 = a0 * DENOM_INV, lg1 = a1 * DENOM_INV;

    float mx = wave_max(fmaxf(lg0, lg1));
    if (lane == 0) s_red[wave] = mx;
    __syncthreads();
    mx = fmaxf(fmaxf(s_red[0], s_red[1]), fmaxf(s_red[2], s_red[3]));
    float e0 = expf(lg0 - mx), e1 = expf(lg1 - mx);
    float ssum = wave_sum(e0 + e1);
    if (lane == 0) s_red[4 + wave] = ssum;
    __syncthreads();
    float inv = 1.f / (s_red[4] + s_red[5] + s_red[6] + s_red[7]);
    float* ap = attn + (size_t)bs * NS;
    ap[tid]       = e0 * inv;
    ap[tid + 256] = e1 * inv;
}

// --- K3: contiguous map_ stream ----------------------------------------
// block = (b, s-chunk of 32, d-pair): reads 2 CONTIGUOUS 64 KB segments of
// map_ (rows s0..s0+31 adjacent for fixed (b,d)). Wave w owns rows w*8..+7;
// attn weights preloaded to regs (reused across the d-pair). Hot loop =
// 2 nt-loads + 8 FMA + 1 LDS store; one transpose-reduce per d.
// bid = ((b*16 + sc)*32 + dp) so 32 consecutive blocks share the attn chunk.
__global__ __launch_bounds__(256) void pool_kernel(
    const float* __restrict__ map_, const float* __restrict__ attn,
    float* __restrict__ m) {
    int bid  = blockIdx.x;
    int dp   = bid & 31;
    int sc   = (bid >> 5) & 15;
    int b    = bid >> 9;
    int s0   = sc * 32;
    int d0   = dp * 2;
    int tid  = threadIdx.x;
    int lane = tid & 63;
    int wave = tid >> 6;

    __shared__ float s_part[32][65];

    // preload this wave's 8 rows of attn weights (t = 4*lane.., 256+4*lane..)
    const f4* attn4 = (const f4*)(attn + ((size_t)b * NS + s0) * NS);
    f4 w0[8], w1[8];
    #pragma unroll
    for (int i = 0; i < 8; ++i) {
        int r = wave * 8 + i;
        w0[i] = attn4[(size_t)r * 128 + lane];
        w1[i] = attn4[(size_t)r * 128 + 64 + lane];
    }

    #pragma unroll
    for (int dd = 0; dd < 2; ++dd) {
        int d = d0 + dd;
        const f4* base = (const f4*)(map_ + (((size_t)b * NMC + d) * NS + s0) * NS);
        #pragma unroll
        for (int i = 0; i < 8; ++i) {
            const f4* rp = base + (size_t)(wave * 8 + i) * 128;
            f4 a0 = __builtin_nontemporal_load(rp + lane);
            f4 a1 = __builtin_nontemporal_load(rp + lane + 64);
            float acc = a0.x * w0[i].x + a0.y * w0[i].y + a0.z * w0[i].z + a0.w * w0[i].w
                      + a1.x * w1[i].x + a1.y * w1[i].y + a1.z * w1[i].z + a1.w * w1[i].w;
            s_part[wave * 8 + i][lane] = acc;
        }
        __syncthreads();
        if (tid < 32) {
            float acc = 0.f;
            #pragma unroll 8
            for (int j = 0; j < 64; ++j) acc += s_part[tid][j];
            m[((size_t)b * NS + s0 + tid) * NMC + d] = acc;
        }
        __syncthreads();
    }
}

// --- K4: tail: pooled = m@Wv+bv, LN, MLP (one block per (b,s), 256 thr) -
__global__ __launch_bounds__(256) void tail_kernel(
    const float* __restrict__ m,
    const float* __restrict__ Wv, const float* __restrict__ bv,
    const float* __restrict__ gamma, const float* __restrict__ beta,
    const float* __restrict__ W1, const float* __restrict__ b1,
    const float* __restrict__ W2, const float* __restrict__ b2,
    float* __restrict__ out) {
    const float LN_EPS = 1e-5f;
    int bs  = blockIdx.x;
    int tid = threadIdx.x;
    int c    = tid & 63;
    int part = tid >> 6;

    __shared__ float s_m[NMC];
    __shared__ float s_score[NMC];
    __shared__ float s_h[NHID];
    __shared__ float s_p[4][65];

    if (tid < NMC) s_m[tid] = m[(size_t)bs * NMC + tid];
    __syncthreads();

    // pooled = m @ Wv + bv, split-K over 4 waves
    {
        float acc = 0.f;
        #pragma unroll
        for (int i = 0; i < 16; ++i) {
            int d = part * 16 + i;
            acc += s_m[d] * Wv[d * NMC + c];
        }
        s_p[part][c] = acc;
    }
    __syncthreads();

    if (tid < NMC) {
        float pooled = bv[tid] + s_p[0][tid] + s_p[1][tid] + s_p[2][tid] + s_p[3][tid];
        float sum   = wave_sum(pooled);
        float sumsq = wave_sum(pooled * pooled);
        float mu  = sum * (1.f / NMC);
        float var = sumsq * (1.f / NMC) - mu * mu;
        float rsig = rsqrtf(var + LN_EPS);
        s_score[tid] = (pooled - mu) * rsig * gamma[tid] + beta[tid];
    }
    __syncthreads();

    // h = relu(score @ W1 + b1): thread tid owns hidden unit tid
    {
        float hacc = b1[tid];
        #pragma unroll 8
        for (int cc = 0; cc < NMC; ++cc) hacc += s_score[cc] * W1[cc * NHID + tid];
        s_h[tid] = fmaxf(hacc, 0.f);
    }
    __syncthreads();

    // out = h @ W2 + b2, split-K over 4 waves
    {
        float acc = 0.f;
        #pragma unroll
        for (int i = 0; i < 64; ++i) {
            int j = part * 64 + i;
            acc += s_h[j] * W2[j * NO + c];
        }
        s_p[part][c] = acc;
    }
    __syncthreads();

    if (tid < NO)
        out[(size_t)bs * NO + tid] =
            b2[tid] + s_p[0][tid] + s_p[1][tid] + s_p[2][tid] + s_p[3][tid];
}

extern "C" void kernel_launch(void* const* d_in, const int* in_sizes, int n_in,
                              void* d_out, int out_size, void* d_ws, size_t ws_size,
                              hipStream_t stream) {
    const float* map_  = (const float*)d_in[0];
    const float* seq   = (const float*)d_in[1];
    const float* Wq    = (const float*)d_in[2];
    const float* bq    = (const float*)d_in[3];
    const float* Wk    = (const float*)d_in[4];
    const float* bk    = (const float*)d_in[5];
    const float* Wv    = (const float*)d_in[6];
    const float* bv    = (const float*)d_in[7];
    const float* gamma = (const float*)d_in[8];
    const float* beta  = (const float*)d_in[9];
    const float* W1    = (const float*)d_in[10];
    const float* b1    = (const float*)d_in[11];
    const float* W2    = (const float*)d_in[12];
    const float* b2    = (const float*)d_in[13];
    float* out = (float*)d_out;

    float* q    = (float*)d_ws;                        // B*S*R
    float* kk   = q    + (size_t)NB * NS * NR;         // B*S*R
    float* attn = kk   + (size_t)NB * NS * NR;         // B*S*S
    float* m    = attn + (size_t)NB * NS * NS;         // B*S*MC

    qk_kernel  <<<NB * NS,      64, 0, stream>>>(seq, Wq, bq, Wk, bk, q, kk);
    attn_kernel<<<NB * NS,     256, 0, stream>>>(q, kk, attn);
    pool_kernel<<<NB * 16 * 32, 256, 0, stream>>>(map_, attn, m);
    tail_kernel<<<NB * NS,     256, 0, stream>>>(m, Wv, bv, gamma, beta,
                                                 W1, b1, W2, b2, out);
}

// Round 5
// 76.341 us; speedup vs baseline: 1.2818x; 1.2818x over previous
//
#include <hip/hip_runtime.h>

#define NB 4      // B
#define NS 512    // S
#define NSC 128   // SC
#define NMC 64    // MC
#define NR 32     // R
#define NO 64     // O
#define NHID 256  // 4*O

typedef float f4 __attribute__((ext_vector_type(4)));

__device__ __forceinline__ float wave_sum(float v) {
    #pragma unroll
    for (int m = 1; m < 64; m <<= 1) v += __shfl_xor(v, m, 64);
    return v;
}
__device__ __forceinline__ float wave_max(float v) {
    #pragma unroll
    for (int m = 1; m < 64; m <<= 1) v = fmaxf(v, __shfl_xor(v, m, 64));
    return v;
}

// --- K1: q,k projections: one block (64 thr) per (b,s) row --------------
__global__ __launch_bounds__(64) void qk_kernel(
    const float* __restrict__ seq,
    const float* __restrict__ Wq, const float* __restrict__ bq,
    const float* __restrict__ Wk, const float* __restrict__ bk,
    float* __restrict__ q, float* __restrict__ k) {
    int bs  = blockIdx.x;
    int tid = threadIdx.x;
    __shared__ float srow[NSC];
    const float* sp = seq + (size_t)bs * NSC;
    srow[tid]      = sp[tid];
    srow[tid + 64] = sp[tid + 64];
    __syncthreads();
    int r = tid & 31;
    const float* W    = (tid < 32) ? Wq : Wk;
    const float* bias = (tid < 32) ? bq : bk;
    float acc = bias[r];
    #pragma unroll 8
    for (int c = 0; c < NSC; ++c) acc += srow[c] * W[c * NR + r];
    float* dst = (tid < 32) ? q : k;
    dst[(size_t)bs * NR + r] = acc;
}

// --- K2: softmax attention rows -> ws (one block per (b,s), 256 thr) ----
__global__ __launch_bounds__(256) void attn_kernel(
    const float* __restrict__ q, const float* __restrict__ k,
    float* __restrict__ attn) {
    const float DENOM_INV = 0.17677669529663687f;  // 1/sqrt(32)
    int bs   = blockIdx.x;
    int b    = bs >> 9;
    int tid  = threadIdx.x;
    int lane = tid & 63;
    int wave = tid >> 6;

    __shared__ float s_q[NR];
    __shared__ float s_red[8];
    if (tid < NR) s_q[tid] = q[(size_t)bs * NR + tid];
    __syncthreads();

    const float* kb = k + (size_t)b * NS * NR;
    const f4* q4 = (const f4*)s_q;
    const f4* k0 = (const f4*)(kb + (size_t)tid * NR);
    const f4* k1 = (const f4*)(kb + (size_t)(tid + 256) * NR);
    float a0 = 0.f, a1 = 0.f;
    #pragma unroll
    for (int r4 = 0; r4 < NR / 4; ++r4) {
        f4 qv = q4[r4], kv0 = k0[r4], kv1 = k1[r4];
        a0 += qv.x * kv0.x + qv.y * kv0.y + qv.z * kv0.z + qv.w * kv0.w;
        a1 += qv.x * kv1.x + qv.y * kv1.y + qv.z * kv1.z + qv.w * kv1.w;
    }
    float lg0 = a0 * DENOM_INV, lg1 = a1 * DENOM_INV;

    float mx = wave_max(fmaxf(lg0, lg1));
    if (lane == 0) s_red[wave] = mx;
    __syncthreads();
    mx = fmaxf(fmaxf(s_red[0], s_red[1]), fmaxf(s_red[2], s_red[3]));
    float e0 = expf(lg0 - mx), e1 = expf(lg1 - mx);
    float ssum = wave_sum(e0 + e1);
    if (lane == 0) s_red[4 + wave] = ssum;
    __syncthreads();
    float inv = 1.f / (s_red[4] + s_red[5] + s_red[6] + s_red[7]);
    float* ap = attn + (size_t)bs * NS;
    ap[tid]       = e0 * inv;
    ap[tid + 256] = e1 * inv;
}

// --- K3: stream + tail: one block per (b,s), 256 thr (R2's stream loop,
// plain loads; prologue = one 2 KB attn-row read; tail GEMVs split-K) ----
__global__ __launch_bounds__(256) void stream_kernel(
    const float* __restrict__ map_, const float* __restrict__ attn,
    const float* __restrict__ Wv, const float* __restrict__ bv,
    const float* __restrict__ gamma, const float* __restrict__ beta,
    const float* __restrict__ W1, const float* __restrict__ b1,
    const float* __restrict__ W2, const float* __restrict__ b2,
    float* __restrict__ out) {
    const float LN_EPS = 1e-5f;
    int bs   = blockIdx.x;
    int b    = bs >> 9;
    int s    = bs & 511;
    int tid  = threadIdx.x;
    int lane = tid & 63;
    int wave = tid >> 6;

    __shared__ float s_part[NMC][65];   // 16.6 KB
    __shared__ float s_m[NMC];
    __shared__ float s_score[NMC];
    __shared__ float s_h[NHID];
    __shared__ float s_p[4][65];

    // prologue: per-lane attn weights (t = 4*lane.., 256+4*lane..)
    const f4* attn4 = (const f4*)(attn + (size_t)bs * NS);
    f4 w0 = attn4[lane];
    f4 w1 = attn4[lane + 64];

    // ---- m[d] = sum_t attn[t] * map_[b,d,s,t]  (the 268 MB stream) ----
    // wave w owns d in [16w, 16w+16); pure load+FMA+LDS-store iterations
    {
        int d0 = wave * 16;
        const f4* base =
            (const f4*)(map_ + (((size_t)b * NMC + d0) * NS + s) * NS);
        #pragma unroll
        for (int i = 0; i < 16; ++i) {
            const f4* rp = base + (size_t)i * (NS * NS / 4);
            f4 a0 = rp[lane];
            f4 a1 = rp[lane + 64];
            float acc = a0.x * w0.x + a0.y * w0.y + a0.z * w0.z + a0.w * w0.w
                      + a1.x * w1.x + a1.y * w1.y + a1.z * w1.z + a1.w * w1.w;
            s_part[d0 + i][lane] = acc;
        }
    }
    __syncthreads();

    // ---- m[d] = sum over 64 lane-partials (65-stride -> conflict-free) --
    if (tid < NMC) {
        float acc = 0.f;
        #pragma unroll 8
        for (int i = 0; i < 64; ++i) acc += s_part[tid][i];
        s_m[tid] = acc;
    }
    __syncthreads();

    // ---- pooled = m @ Wv + bv, split-K over 4 waves ----
    {
        int c = tid & 63, part = tid >> 6;
        float acc = 0.f;
        #pragma unroll
        for (int i = 0; i < 16; ++i) {
            int d = part * 16 + i;
            acc += s_m[d] * Wv[d * NMC + c];
        }
        s_p[part][c] = acc;
    }
    __syncthreads();

    // ---- LN (tid<64) ----
    if (tid < NMC) {
        float pooled = bv[tid] + s_p[0][tid] + s_p[1][tid] + s_p[2][tid] + s_p[3][tid];
        float sum   = wave_sum(pooled);
        float sumsq = wave_sum(pooled * pooled);
        float mu  = sum * (1.f / NMC);
        float var = sumsq * (1.f / NMC) - mu * mu;
        float rsig = rsqrtf(var + LN_EPS);
        s_score[tid] = (pooled - mu) * rsig * gamma[tid] + beta[tid];
    }
    __syncthreads();

    // ---- h = relu(score @ W1 + b1): thread tid owns hidden unit tid ----
    {
        float hacc = b1[tid];
        #pragma unroll 8
        for (int c = 0; c < NMC; ++c) hacc += s_score[c] * W1[c * NHID + tid];
        s_h[tid] = fmaxf(hacc, 0.f);
    }
    __syncthreads();

    // ---- out = h @ W2 + b2, split-K over 4 waves ----
    {
        int c = tid & 63, part = tid >> 6;
        float acc = 0.f;
        #pragma unroll
        for (int i = 0; i < 64; ++i) {
            int j = part * 64 + i;
            acc += s_h[j] * W2[j * NO + c];
        }
        s_p[part][c] = acc;
    }
    __syncthreads();

    if (tid < NO)
        out[(size_t)bs * NO + tid] =
            b2[tid] + s_p[0][tid] + s_p[1][tid] + s_p[2][tid] + s_p[3][tid];
}

extern "C" void kernel_launch(void* const* d_in, const int* in_sizes, int n_in,
                              void* d_out, int out_size, void* d_ws, size_t ws_size,
                              hipStream_t stream) {
    const float* map_  = (const float*)d_in[0];
    const float* seq   = (const float*)d_in[1];
    const float* Wq    = (const float*)d_in[2];
    const float* bq    = (const float*)d_in[3];
    const float* Wk    = (const float*)d_in[4];
    const float* bk    = (const float*)d_in[5];
    const float* Wv    = (const float*)d_in[6];
    const float* bv    = (const float*)d_in[7];
    const float* gamma = (const float*)d_in[8];
    const float* beta  = (const float*)d_in[9];
    const float* W1    = (const float*)d_in[10];
    const float* b1    = (const float*)d_in[11];
    const float* W2    = (const float*)d_in[12];
    const float* b2    = (const float*)d_in[13];
    float* out = (float*)d_out;

    float* q    = (float*)d_ws;                        // B*S*R
    float* kk   = q    + (size_t)NB * NS * NR;         // B*S*R
    float* attn = kk   + (size_t)NB * NS * NR;         // B*S*S

    qk_kernel    <<<NB * NS,  64, 0, stream>>>(seq, Wq, bq, Wk, bk, q, kk);
    attn_kernel  <<<NB * NS, 256, 0, stream>>>(q, kk, attn);
    stream_kernel<<<NB * NS, 256, 0, stream>>>(map_, attn, Wv, bv, gamma, beta,
                                               W1, b1, W2, b2, out);
}